// Round 6
// baseline (180.569 us; speedup 1.0000x reference)
//
#include <hip/hip_runtime.h>

#define BATCH 4096
#define DIM 4096
#define NSPLIT 64
#define ROWS_PB 128
#define NCHUNK 32            // BATCH / ROWS_PB
#define SPB 4                // splits per K1 block
#define SGRP 16              // NSPLIT / SPB
#define BN_EPS 1e-3f
#define XS_LD 264            // 256 + 8 pad: rows stay 16B-aligned, b128 reads conflict-free

typedef __attribute__((ext_vector_type(8))) short bf16x8;
typedef __attribute__((ext_vector_type(8))) unsigned short ushort8;
typedef __attribute__((ext_vector_type(4))) float f32x4;

__device__ inline unsigned short f2bf(float f) {
    union { float f; unsigned int u; } c; c.f = f;
    unsigned int u = c.u;
    u += 0x7FFFu + ((u >> 16) & 1u);   // round-to-nearest-even
    return (unsigned short)(u >> 16);
}

__device__ inline float bf2f(unsigned short h) {
    union { unsigned int u; float f; } c;
    c.u = (unsigned int)h << 16;
    return c.f;
}

// K1: GEMM once, DRAM-page-friendly. Block = 128 rows x 4 splits (256 cols):
// the x stage reads 1KB CONTIGUOUS per row (vs 256B before) -> ~4x better
// DRAM page locality, which R3-R5 showed is the binding constraint.
// 512 threads = 8 waves; wave (sp, hw) computes split sp's 64-row half hw.
// Emits R4-layout part partials (1 MiB, validated) and bf16 y packed into
// each split's own out-tile (unit mapping below, K2 decodes symmetrically).
// Bias dropped: cancels exactly under BatchNorm mean subtraction.
__global__ __launch_bounds__(512) void gemm_stats(
    const float* __restrict__ x, const float* __restrict__ w,
    float* __restrict__ part, float* __restrict__ out)
{
    __shared__ unsigned short xs[ROWS_PB][XS_LD];   // 67.6 KB
    __shared__ unsigned short wt[SPB][64][72];      // 36.9 KB
    __shared__ float red1[8][64], red2[8][64];      //  4.1 KB

    const int sg = blockIdx.y;            // split group (4 splits)
    const int r0 = blockIdx.x * ROWS_PB;
    const int t  = threadIdx.x;
    const int lane = t & 63, wave = t >> 6;
    const int quad = lane >> 4, l16 = lane & 15;
    const int sp = wave >> 1;             // split within group (0..3)
    const int hw = wave & 1;              // row half (0..1)
    const int s  = sg * SPB + sp;         // global split for this wave

    // stage X: 128 rows x 256 cols fp32 -> bf16; per instr: 8 rows x 1KB runs
    #pragma unroll
    for (int it = 0; it < 16; it++) {
        int i = t + it * 512;
        int row = i >> 6, c4 = i & 63;
        float4 v = *(const float4*)(x + (size_t)(r0 + row) * DIM + sg*256 + c4*4);
        ushort4 u;
        u.x = f2bf(v.x); u.y = f2bf(v.y); u.z = f2bf(v.z); u.w = f2bf(v.w);
        *(ushort4*)&xs[row][c4*4] = u;
    }

    // stage W for the 4 splits (transposed, fp32 -> bf16)
    #pragma unroll
    for (int it = 0; it < 8; it++) {
        int i = t + it * 512;
        int spw = i >> 10, k = (i >> 4) & 63, c4 = i & 15;
        int sw = sg * SPB + spw;
        float4 v = *(const float4*)(w + (size_t)(sw*64 + k) * DIM + sw*64 + c4*4);
        wt[spw][c4*4 + 0][k] = f2bf(v.x);
        wt[spw][c4*4 + 1][k] = f2bf(v.y);
        wt[spw][c4*4 + 2][k] = f2bf(v.z);
        wt[spw][c4*4 + 3][k] = f2bf(v.w);
    }
    __syncthreads();

    // fragments from LDS (b128, conflict-free: row strides 132/36 words -> 4-aligned
    // start banks, uniform 8 word-accesses per bank = minimum)
    bf16x8 af[4][2], bfr[4][2];
    #pragma unroll
    for (int rt = 0; rt < 4; rt++)
        #pragma unroll
        for (int kk = 0; kk < 2; kk++)
            af[rt][kk] = *(const bf16x8*)&xs[hw*64 + rt*16 + l16][sp*64 + kk*32 + quad*8];
    #pragma unroll
    for (int ct = 0; ct < 4; ct++)
        #pragma unroll
        for (int kk = 0; kk < 2; kk++)
            bfr[ct][kk] = *(const bf16x8*)&wt[sp][ct*16 + l16][kk*32 + quad*8];

    f32x4 acc[4][4];
    #pragma unroll
    for (int rt = 0; rt < 4; rt++)
        #pragma unroll
        for (int ct = 0; ct < 4; ct++)
            acc[rt][ct] = (f32x4){0.f, 0.f, 0.f, 0.f};

    #pragma unroll
    for (int kk = 0; kk < 2; kk++)
        #pragma unroll
        for (int rt = 0; rt < 4; rt++)
            #pragma unroll
            for (int ct = 0; ct < 4; ct++)
                acc[rt][ct] = __builtin_amdgcn_mfma_f32_16x16x32_bf16(
                    af[rt][kk], bfr[ct][kk], acc[rt][ct], 0, 0, 0);

    // pack y -> bf16 into split s's out-tile (rows r0..r0+63 region, 16 units/row).
    // unit u = (rt*2+jp)*128 + hw*64 + lane; value k in unit: ct = jp*2 + (k>>2),
    // r = k&3, y-row = r0 + hw*64 + rt*16 + quad*4 + r, y-col = ct*16 + l16.
    #pragma unroll
    for (int rt = 0; rt < 4; rt++)
        #pragma unroll
        for (int jp = 0; jp < 2; jp++) {
            const f32x4 a0 = acc[rt][jp*2 + 0];
            const f32x4 a1 = acc[rt][jp*2 + 1];
            ushort8 pk;
            pk[0] = f2bf(a0[0]); pk[1] = f2bf(a0[1]);
            pk[2] = f2bf(a0[2]); pk[3] = f2bf(a0[3]);
            pk[4] = f2bf(a1[0]); pk[5] = f2bf(a1[1]);
            pk[6] = f2bf(a1[2]); pk[7] = f2bf(a1[3]);
            int u = (rt*2 + jp)*128 + hw*64 + lane;
            unsigned short* dst =
                (unsigned short*)(out + (size_t)(r0 + (u >> 4)) * DIM + s*64)
                + (u & 15) * 8;
            *(ushort8*)dst = pk;
        }

    // per-wave column partials (64 rows each) -> shuffle -> LDS
    float s1[4], s2[4];
    #pragma unroll
    for (int ct = 0; ct < 4; ct++) { s1[ct] = 0.f; s2[ct] = 0.f; }
    #pragma unroll
    for (int rt = 0; rt < 4; rt++)
        #pragma unroll
        for (int ct = 0; ct < 4; ct++)
            #pragma unroll
            for (int r = 0; r < 4; r++) {
                float v = acc[rt][ct][r];
                s1[ct] += v; s2[ct] += v * v;
            }
    #pragma unroll
    for (int ct = 0; ct < 4; ct++) {
        float a = s1[ct], b = s2[ct];
        a += __shfl_xor(a, 16); b += __shfl_xor(b, 16);
        a += __shfl_xor(a, 32); b += __shfl_xor(b, 32);
        if (quad == 0) {
            red1[wave][ct*16 + l16] = a;
            red2[wave][ct*16 + l16] = b;
        }
    }
    __syncthreads();

    // combine the two row-half waves of each split; R4 part layout (1 MiB)
    if (t < 256) {
        int sp2 = t >> 6, col = t & 63;
        float a = red1[sp2*2 + 0][col] + red1[sp2*2 + 1][col];
        float b = red2[sp2*2 + 0][col] + red2[sp2*2 + 1][col];
        size_t base = (size_t)((sg*SPB + sp2) * NCHUNK + blockIdx.x) * 128;
        part[base + col]      = a;
        part[base + 64 + col] = b;
    }
}

// K2: finalize stats (parallel reduce over 32 partials/split), read back the
// tile's bf16 y (L3-hot), BN + ReLU, fp32 scatter store. vmcnt(0)+barrier
// orders tile-read before any tile-overwrite.
__global__ __launch_bounds__(256) void bn_apply(
    const float* __restrict__ part, const float* __restrict__ gamma,
    const float* __restrict__ beta, float* __restrict__ out)
{
    __shared__ float redA[4][64], redB[4][64];
    __shared__ float scol[64], shcol[64];

    const int s  = blockIdx.y;
    const int r0 = blockIdx.x * ROWS_PB;
    const int t  = threadIdx.x;
    const int lane = t & 63, wave = t >> 6;

    // load own y tile early (4 x 16B per thread, issued before the reduce)
    ushort8 yv[4];
    #pragma unroll
    for (int jj = 0; jj < 4; jj++) {
        int u = jj*256 + t;
        const unsigned short* src =
            (const unsigned short*)(out + (size_t)(r0 + (u >> 4)) * DIM + s*64)
            + (u & 15) * 8;
        yv[jj] = *(const ushort8*)src;
    }

    // parallel part-reduce: wave g covers chunks g*8..g*8+7, col = lane
    {
        float a = 0.f, b = 0.f;
        #pragma unroll
        for (int p8 = 0; p8 < 8; p8++) {
            int p = wave*8 + p8;
            size_t base = (size_t)(s * NCHUNK + p) * 128;
            a += part[base + lane];
            b += part[base + 64 + lane];
        }
        redA[wave][lane] = a;
        redB[wave][lane] = b;
    }

    // all global loads (y + part) must have landed before any thread stores
    asm volatile("s_waitcnt vmcnt(0)" ::: "memory");
    __syncthreads();

    if (t < 64) {
        float a = redA[0][t] + redA[1][t] + redA[2][t] + redA[3][t];
        float b = redB[0][t] + redB[1][t] + redB[2][t] + redB[3][t];
        float mean = a * (1.f / BATCH);
        float var  = b * (1.f / BATCH) - mean * mean;
        float rstd = rsqrtf(var + BN_EPS);
        float sc = gamma[s*64 + t] * rstd;
        scol[t]  = sc;
        shcol[t] = beta[s*64 + t] - mean * sc;
    }
    __syncthreads();

    // decode units (matched to K1's mapping), BN + ReLU, store fp32
    #pragma unroll
    for (int jj = 0; jj < 4; jj++) {
        int u   = jj*256 + t;
        int idx = u >> 7;            // rt*2 + jp
        int tt  = u & 127;
        int hw  = tt >> 6;
        int ln  = tt & 63;
        int qd  = ln >> 4, lw = ln & 15;
        int rt  = idx >> 1, jp = idx & 1;
        #pragma unroll
        for (int k = 0; k < 8; k++) {
            int ct  = jp*2 + (k >> 2);
            int r   = k & 3;
            int row = r0 + hw*64 + rt*16 + qd*4 + r;
            int col = ct*16 + lw;
            float v = fmaxf(fmaf(bf2f((unsigned short)yv[jj][k]),
                                 scol[col], shcol[col]), 0.f);
            out[(size_t)row * DIM + s*64 + col] = v;
        }
    }
}

extern "C" void kernel_launch(void* const* d_in, const int* in_sizes, int n_in,
                              void* d_out, int out_size, void* d_ws, size_t ws_size,
                              hipStream_t stream) {
    const float* x     = (const float*)d_in[0];
    const float* w     = (const float*)d_in[1];
    // d_in[2] = bias: cancels exactly in BatchNorm (mean subtraction) — unused
    const float* gamma = (const float*)d_in[3];
    const float* beta  = (const float*)d_in[4];
    float* out  = (float*)d_out;
    float* part = (float*)d_ws;    // 1 MiB — the baseline-validated footprint

    gemm_stats<<<dim3(NCHUNK, SGRP), 512, 0, stream>>>(x, w, part, out);
    bn_apply<<<dim3(NCHUNK, NSPLIT), 256, 0, stream>>>(part, gamma, beta, out);
}